// Round 7
// baseline (136.158 us; speedup 1.0000x reference)
//
#include <hip/hip_runtime.h>
#include <math.h>

// ConsistencyLoss: KL( softmax(soft/T) || softmax(logits/T) ) * T^2, batchmean.
// B = 4,194,304, C = 5, T = 3.
//
// R7: barrier-free kernel1. Wave w stages LDS float4s [320w,320w+320) via
// global_load_lds and its own lanes consume exactly that range (quads
// [64w,64w+64)) -> producer==consumer per wave, so the block-wide
// __syncthreads (vmcnt-drain restart for all 8 waves) is replaced by a
// per-wave s_waitcnt vmcnt(0). One partial per wave to d_ws (no cross-wave
// LDS reduce), reduced by a tiny second kernel.

constexpr int   kC     = 5;
constexpr float kInvT  = 1.0f / 3.0f;
constexpr float kExp13 = 1.3956124250860895f;   // e^{1/3}
constexpr int   kBatch = 4194304;

constexpr int kThreads      = 512;                          // 8 waves
constexpr int kQuadsPerTile = 512;                          // 2048 samples/block
constexpr int kTileVec4     = kQuadsPerTile * 5;            // 2560 float4 = 40 KB
constexpr int kBlocks       = (kBatch / 4) / kQuadsPerTile; // 2048
constexpr int kNumPartials  = kBlocks * 8;                  // one per wave = 16384

__device__ __forceinline__ float kl_quad(float4 P0, float4 P1, float4 P2,
                                         float4 P3, float4 P4, float4 s4) {
    const float v[20] = {P0.x, P0.y, P0.z, P0.w,
                         P1.x, P1.y, P1.z, P1.w,
                         P2.x, P2.y, P2.z, P2.w,
                         P3.x, P3.y, P3.z, P3.w,
                         P4.x, P4.y, P4.z, P4.w};
    const float ss[4] = {s4.x, s4.y, s4.z, s4.w};

    float acc = 0.0f;
    #pragma unroll
    for (int r = 0; r < 4; ++r) {
        const float s  = ss[r];
        const float l0 = v[r * 5 + 0], l1 = v[r * 5 + 1], l2 = v[r * 5 + 2],
                    l3 = v[r * 5 + 3], l4 = v[r * 5 + 4];

        // --- soft target geometry (matches reference exactly) ---
        const float sc     = fminf(fmaxf(s * 5.0f, 0.0f), 4.0f);
        const int   idx    = (int)sc;                    // floor, s >= 0
        const float center = ((float)idx + 0.5f) * 0.2f;
        float       d      = fabsf(s - center) * 5.0f;
        const bool  lo     = (idx > 0) && (s < center);
        const bool  hi     = (idx < kC - 1) && (s > center);
        const bool  nb     = lo || hi;
        d = nb ? d : 0.0f;
        const int nbi = idx + (hi ? 1 : 0) - (lo ? 1 : 0);

        // soft = {1-d at idx, d at nbi, 0 elsewhere};  e_main = e^{1/3}/e_nb
        const float e_nb   = __expf(d * kInvT);
        const float e_main = kExp13 * __builtin_amdgcn_rcpf(e_nb);

        const float S = l0 + l1 + l2 + l3 + l4;
        const float l_main = (idx == 0) ? l0 : (idx == 1) ? l1 :
                             (idx == 2) ? l2 : (idx == 3) ? l3 : l4;
        const float l_nb   = (nbi == 0) ? l0 : (nbi == 1) ? l1 :
                             (nbi == 2) ? l2 : (nbi == 3) ? l3 : l4;

        const float Zq = __expf(l0 * kInvT) + __expf(l1 * kInvT) +
                         __expf(l2 * kInvT) + __expf(l3 * kInvT) +
                         __expf(l4 * kInvT);

        const float Zp  = e_main + e_nb + 3.0f;
        const float rZp = __builtin_amdgcn_rcpf(Zp);
        const float Spa = e_main * (1.0f - d) + e_nb * d;
        const float Spl = e_main * l_main + e_nb * l_nb + (S - l_main - l_nb);

        acc += kInvT * (Spa - Spl) * rZp + __logf(Zq * rZp);
    }
    return acc;
}

__global__ __launch_bounds__(kThreads) void kl_partial_kernel(
    const float* __restrict__ score,
    const float* __restrict__ logits,
    float* __restrict__ partial) {

    __shared__ float4 slog4[kTileVec4];          // 40 KB, 16B-aligned by type

    const int t    = threadIdx.x;
    const int wave = t >> 6;                     // 0..7
    const int lane = t & 63;
    const int tile_quad0 = blockIdx.x * kQuadsPerTile;

    // --- wave-local async staging: wave w owns float4s [320w, 320w+320) ---
    // (exactly the range its own lanes consume -> no block barrier needed)
    const float4* gsrc = reinterpret_cast<const float4*>(logits + (size_t)tile_quad0 * 20);
    #pragma unroll
    for (int j = 0; j < 5; ++j) {
        const int base = wave * 320 + j * 64;    // uniform base + lane*16
        __builtin_amdgcn_global_load_lds(
            (const __attribute__((address_space(1))) void*)(gsrc + base + lane),
            (__attribute__((address_space(3))) void*)(&slog4[base]),
            16, 0, 0);
    }

    // score for this thread's quad (coalesced float4 load; drained by same waitcnt)
    const float4* gsc = reinterpret_cast<const float4*>(score + (size_t)tile_quad0 * 4);
    const float4 sA = gsc[t];

    // per-wave drain of the 5 DMA loads + score load; no __syncthreads
    __builtin_amdgcn_s_waitcnt(0x0f70);          // vmcnt(0), lgkm/exp unlimited
    __builtin_amdgcn_wave_barrier();             // pin: no ds_read hoisted above

    // quad t: float4s [5t, 5t+5) — start bank (20t+4j)%32; each 8-lane group
    // covers all 32 banks -> conflict-free b128 reads (2-way wave alias free).
    const int a0 = t * 5;
    float acc = kl_quad(slog4[a0], slog4[a0 + 1], slog4[a0 + 2],
                        slog4[a0 + 3], slog4[a0 + 4], sA);

    // --- wave (64-lane) shuffle reduction; one partial per wave ---
    #pragma unroll
    for (int off = 32; off > 0; off >>= 1) acc += __shfl_down(acc, off, 64);
    if (lane == 0) partial[blockIdx.x * 8 + wave] = acc;
}

__global__ __launch_bounds__(256) void kl_final_kernel(
    const float* __restrict__ partial,
    float* __restrict__ out) {
    const int t = threadIdx.x;
    // 16384 partials = 4096 float4s; thread t sums 16 float4s at stride 256
    const float4* p4 = reinterpret_cast<const float4*>(partial);
    float acc = 0.0f;
    #pragma unroll
    for (int j = 0; j < 16; ++j) {
        const float4 a = p4[t + 256 * j];
        acc += a.x + a.y + a.z + a.w;
    }

    #pragma unroll
    for (int off = 32; off > 0; off >>= 1) acc += __shfl_down(acc, off, 64);

    __shared__ float wsum[4];
    if ((t & 63) == 0) wsum[t >> 6] = acc;
    __syncthreads();
    if (t == 0) {
        out[0] = (wsum[0] + wsum[1] + wsum[2] + wsum[3]) * (9.0f / (float)kBatch);
    }
}

extern "C" void kernel_launch(void* const* d_in, const int* in_sizes, int n_in,
                              void* d_out, int out_size, void* d_ws, size_t ws_size,
                              hipStream_t stream) {
    const float* score  = (const float*)d_in[0];   // quality_score [B]
    const float* logits = (const float*)d_in[1];   // class_logits [B,5]
    float* out     = (float*)d_out;
    float* partial = (float*)d_ws;                 // kNumPartials floats, rewritten every call

    kl_partial_kernel<<<kBlocks, kThreads, 0, stream>>>(score, logits, partial);
    kl_final_kernel<<<1, 256, 0, stream>>>(partial, out);
}

// Round 8
// 135.840 us; speedup vs baseline: 1.0023x; 1.0023x over previous
//
#include <hip/hip_runtime.h>
#include <math.h>

// ConsistencyLoss: KL( softmax(soft/T) || softmax(logits/T) ) * T^2, batchmean.
// B = 4,194,304, C = 5, T = 3.
//
// R8: single-kernel. Kernel1 structure identical to R6 (best: LDS-staged via
// global_load_lds width=16, 512 thr, 40 KB tile, __syncthreads). Final
// reduction fused via 8-byte mailboxes in d_ws: each block atomically stores
// (MAGIC<<32)|float_bits (device scope, relaxed — value+flag in one atomic,
// no fence needed); block 0 polls all mailboxes after its own tile and
// writes out. Poison 0xAA.. != MAGIC and memset-0 != MAGIC, so stale ws
// never reads as ready.

constexpr int   kC     = 5;
constexpr float kInvT  = 1.0f / 3.0f;
constexpr float kExp13 = 1.3956124250860895f;   // e^{1/3}
constexpr int   kBatch = 4194304;

constexpr int kThreads      = 512;                          // 8 waves
constexpr int kQuadsPerTile = 512;                          // 2048 samples/block
constexpr int kTileVec4     = kQuadsPerTile * 5;            // 2560 float4 = 40 KB
constexpr int kBlocks       = (kBatch / 4) / kQuadsPerTile; // 2048
constexpr unsigned int kMagic = 0xC0FFEE42u;

__device__ __forceinline__ float kl_quad(float4 P0, float4 P1, float4 P2,
                                         float4 P3, float4 P4, float4 s4) {
    const float v[20] = {P0.x, P0.y, P0.z, P0.w,
                         P1.x, P1.y, P1.z, P1.w,
                         P2.x, P2.y, P2.z, P2.w,
                         P3.x, P3.y, P3.z, P3.w,
                         P4.x, P4.y, P4.z, P4.w};
    const float ss[4] = {s4.x, s4.y, s4.z, s4.w};

    float acc = 0.0f;
    #pragma unroll
    for (int r = 0; r < 4; ++r) {
        const float s  = ss[r];
        const float l0 = v[r * 5 + 0], l1 = v[r * 5 + 1], l2 = v[r * 5 + 2],
                    l3 = v[r * 5 + 3], l4 = v[r * 5 + 4];

        // --- soft target geometry (matches reference exactly) ---
        const float sc     = fminf(fmaxf(s * 5.0f, 0.0f), 4.0f);
        const int   idx    = (int)sc;                    // floor, s >= 0
        const float center = ((float)idx + 0.5f) * 0.2f;
        float       d      = fabsf(s - center) * 5.0f;
        const bool  lo     = (idx > 0) && (s < center);
        const bool  hi     = (idx < kC - 1) && (s > center);
        const bool  nb     = lo || hi;
        d = nb ? d : 0.0f;
        const int nbi = idx + (hi ? 1 : 0) - (lo ? 1 : 0);

        // soft = {1-d at idx, d at nbi, 0 elsewhere};  e_main = e^{1/3}/e_nb
        const float e_nb   = __expf(d * kInvT);
        const float e_main = kExp13 * __builtin_amdgcn_rcpf(e_nb);

        const float S = l0 + l1 + l2 + l3 + l4;
        const float l_main = (idx == 0) ? l0 : (idx == 1) ? l1 :
                             (idx == 2) ? l2 : (idx == 3) ? l3 : l4;
        const float l_nb   = (nbi == 0) ? l0 : (nbi == 1) ? l1 :
                             (nbi == 2) ? l2 : (nbi == 3) ? l3 : l4;

        const float Zq = __expf(l0 * kInvT) + __expf(l1 * kInvT) +
                         __expf(l2 * kInvT) + __expf(l3 * kInvT) +
                         __expf(l4 * kInvT);

        const float Zp  = e_main + e_nb + 3.0f;
        const float rZp = __builtin_amdgcn_rcpf(Zp);
        const float Spa = e_main * (1.0f - d) + e_nb * d;
        const float Spl = e_main * l_main + e_nb * l_nb + (S - l_main - l_nb);

        acc += kInvT * (Spa - Spl) * rZp + __logf(Zq * rZp);
    }
    return acc;
}

__global__ __launch_bounds__(kThreads) void kl_kernel(
    const float* __restrict__ score,
    const float* __restrict__ logits,
    unsigned long long* __restrict__ mailbox,   // kBlocks entries in d_ws
    float* __restrict__ out) {

    __shared__ float4 slog4[kTileVec4];          // 40 KB, 16B-aligned by type

    const int t    = threadIdx.x;
    const int wave = t >> 6;                     // 0..7
    const int lane = t & 63;
    const int tile_quad0 = blockIdx.x * kQuadsPerTile;

    // --- async staging: 2560 float4s, 8 waves x 5 iters x 64 lanes ---
    const float4* gsrc = reinterpret_cast<const float4*>(logits + (size_t)tile_quad0 * 20);
    #pragma unroll
    for (int j = 0; j < 5; ++j) {
        const int base = wave * 320 + j * 64;    // uniform base + lane*16
        __builtin_amdgcn_global_load_lds(
            (const __attribute__((address_space(1))) void*)(gsrc + base + lane),
            (__attribute__((address_space(3))) void*)(&slog4[base]),
            16, 0, 0);
    }

    // score for this thread's quad (coalesced float4 load, overlaps DMA)
    const float4* gsc = reinterpret_cast<const float4*>(score + (size_t)tile_quad0 * 4);
    const float4 sA = gsc[t];

    __syncthreads();   // drains vmcnt (global_load_lds) for all waves

    // quad t: float4s [5t, 5t+5) — conflict-free b128 reads
    const int a0 = t * 5;
    float acc = kl_quad(slog4[a0], slog4[a0 + 1], slog4[a0 + 2],
                        slog4[a0 + 3], slog4[a0 + 4], sA);

    // --- wave (64-lane) shuffle reduction ---
    #pragma unroll
    for (int off = 32; off > 0; off >>= 1) acc += __shfl_down(acc, off, 64);

    __shared__ float wsum[8];
    if (lane == 0) wsum[wave] = acc;
    __syncthreads();

    if (t == 0) {
        float b = 0.0f;
        #pragma unroll
        for (int w = 0; w < 8; ++w) b += wsum[w];
        const unsigned long long pkt =
            ((unsigned long long)kMagic << 32) | (unsigned long long)__float_as_uint(b);
        __hip_atomic_store(&mailbox[blockIdx.x], pkt,
                           __ATOMIC_RELAXED, __HIP_MEMORY_SCOPE_AGENT);
    }

    // --- block 0: poll all mailboxes, reduce, write out ---
    if (blockIdx.x != 0) return;

    float facc = 0.0f;
    #pragma unroll
    for (int j = 0; j < kBlocks / kThreads; ++j) {       // 4 mailboxes/thread
        const int idx = t * (kBlocks / kThreads) + j;
        unsigned long long v;
        while (true) {
            v = __hip_atomic_load(&mailbox[idx],
                                  __ATOMIC_RELAXED, __HIP_MEMORY_SCOPE_AGENT);
            if ((unsigned int)(v >> 32) == kMagic) break;
            __builtin_amdgcn_s_sleep(1);
        }
        facc += __uint_as_float((unsigned int)v);
    }

    #pragma unroll
    for (int off = 32; off > 0; off >>= 1) facc += __shfl_down(facc, off, 64);

    __shared__ float fsum[8];
    if (lane == 0) fsum[wave] = facc;
    __syncthreads();
    if (t == 0) {
        float b = 0.0f;
        #pragma unroll
        for (int w = 0; w < 8; ++w) b += fsum[w];
        out[0] = b * (9.0f / (float)kBatch);   // * T^2 / B
    }
}

extern "C" void kernel_launch(void* const* d_in, const int* in_sizes, int n_in,
                              void* d_out, int out_size, void* d_ws, size_t ws_size,
                              hipStream_t stream) {
    const float* score  = (const float*)d_in[0];   // quality_score [B]
    const float* logits = (const float*)d_in[1];   // class_logits [B,5]
    float* out = (float*)d_out;
    unsigned long long* mailbox = (unsigned long long*)d_ws;  // kBlocks * 8 B

    kl_kernel<<<kBlocks, kThreads, 0, stream>>>(score, logits, mailbox, out);
}

// Round 9
// 135.448 us; speedup vs baseline: 1.0052x; 1.0029x over previous
//
#include <hip/hip_runtime.h>
#include <math.h>

// ConsistencyLoss: KL( softmax(soft/T) || softmax(logits/T) ) * T^2, batchmean.
// B = 4,194,304, C = 5, T = 3.
//
// FINAL (revert to R6, the best-measured variant: 134.0 us total).
// Structure: 512 thr/block (8 waves), 40 KB LDS tile (2048 samples),
// logits staged HBM->LDS via __builtin_amdgcn_global_load_lds width=16
// (direct DMA, no VGPR round-trip; wave-uniform base + lane*16 layout),
// 32 waves/CU occupancy, conflict-free b128 LDS reads (start bank
// (20t+4j)%32 covers all 32 banks per 8-lane group), per-wave shuffle
// reduce -> per-block partial in d_ws -> tiny final-reduce kernel.
//
// Session evidence (R3-R8):
//  - direct 80-B-strided float4 loads: 63 us (transaction-rate bound, 800 GB/s)
//  - LDS-staged: ~33 us (R5/R6); barrier-free waitcnt (R7) and fused
//    mailbox reduce (R8) both neutral -> kernel window is HBM-channel
//    bound (shared with the harness's 335 MB ws-poison writeback drain).
//  - compulsory read = 100.7 MB (irreducible); compute ~4 us (hidden);
//    LDS conflicts 0; absmax 0.0 throughout.

constexpr int   kC     = 5;
constexpr float kInvT  = 1.0f / 3.0f;
constexpr float kExp13 = 1.3956124250860895f;   // e^{1/3}
constexpr int   kBatch = 4194304;

constexpr int kThreads      = 512;                          // 8 waves
constexpr int kQuadsPerTile = 512;                          // 2048 samples/block
constexpr int kTileVec4     = kQuadsPerTile * 5;            // 2560 float4 = 40 KB
constexpr int kBlocks       = (kBatch / 4) / kQuadsPerTile; // 2048

__device__ __forceinline__ float kl_quad(float4 P0, float4 P1, float4 P2,
                                         float4 P3, float4 P4, float4 s4) {
    const float v[20] = {P0.x, P0.y, P0.z, P0.w,
                         P1.x, P1.y, P1.z, P1.w,
                         P2.x, P2.y, P2.z, P2.w,
                         P3.x, P3.y, P3.z, P3.w,
                         P4.x, P4.y, P4.z, P4.w};
    const float ss[4] = {s4.x, s4.y, s4.z, s4.w};

    float acc = 0.0f;
    #pragma unroll
    for (int r = 0; r < 4; ++r) {
        const float s  = ss[r];
        const float l0 = v[r * 5 + 0], l1 = v[r * 5 + 1], l2 = v[r * 5 + 2],
                    l3 = v[r * 5 + 3], l4 = v[r * 5 + 4];

        // --- soft target geometry (matches reference exactly) ---
        const float sc     = fminf(fmaxf(s * 5.0f, 0.0f), 4.0f);
        const int   idx    = (int)sc;                    // floor, s >= 0
        const float center = ((float)idx + 0.5f) * 0.2f;
        float       d      = fabsf(s - center) * 5.0f;
        const bool  lo     = (idx > 0) && (s < center);
        const bool  hi     = (idx < kC - 1) && (s > center);
        const bool  nb     = lo || hi;
        d = nb ? d : 0.0f;
        const int nbi = idx + (hi ? 1 : 0) - (lo ? 1 : 0);

        // soft = {1-d at idx, d at nbi, 0 elsewhere};  e_main = e^{1/3}/e_nb
        const float e_nb   = __expf(d * kInvT);
        const float e_main = kExp13 * __builtin_amdgcn_rcpf(e_nb);

        const float S = l0 + l1 + l2 + l3 + l4;
        const float l_main = (idx == 0) ? l0 : (idx == 1) ? l1 :
                             (idx == 2) ? l2 : (idx == 3) ? l3 : l4;
        const float l_nb   = (nbi == 0) ? l0 : (nbi == 1) ? l1 :
                             (nbi == 2) ? l2 : (nbi == 3) ? l3 : l4;

        const float Zq = __expf(l0 * kInvT) + __expf(l1 * kInvT) +
                         __expf(l2 * kInvT) + __expf(l3 * kInvT) +
                         __expf(l4 * kInvT);

        const float Zp  = e_main + e_nb + 3.0f;
        const float rZp = __builtin_amdgcn_rcpf(Zp);
        const float Spa = e_main * (1.0f - d) + e_nb * d;
        const float Spl = e_main * l_main + e_nb * l_nb + (S - l_main - l_nb);

        acc += kInvT * (Spa - Spl) * rZp + __logf(Zq * rZp);
    }
    return acc;
}

__global__ __launch_bounds__(kThreads) void kl_partial_kernel(
    const float* __restrict__ score,
    const float* __restrict__ logits,
    float* __restrict__ partial) {

    __shared__ float4 slog4[kTileVec4];          // 40 KB, 16B-aligned by type

    const int t    = threadIdx.x;
    const int wave = t >> 6;                     // 0..7
    const int lane = t & 63;
    const int tile_quad0 = blockIdx.x * kQuadsPerTile;

    // --- async staging: 2560 float4s, 8 waves x 5 iters x 64 lanes ---
    // wave w owns float4 range [w*320, (w+1)*320); iter j is a contiguous
    // 64-float4 (1 KB) chunk: LDS dst = uniform base + lane*16 (HW pattern).
    const float4* gsrc = reinterpret_cast<const float4*>(logits + (size_t)tile_quad0 * 20);
    #pragma unroll
    for (int j = 0; j < 5; ++j) {
        const int base = wave * 320 + j * 64;
        __builtin_amdgcn_global_load_lds(
            (const __attribute__((address_space(1))) void*)(gsrc + base + lane),
            (__attribute__((address_space(3))) void*)(&slog4[base]),
            16, 0, 0);
    }

    // score for this thread's quad (coalesced float4 load, overlaps DMA)
    const float4* gsc = reinterpret_cast<const float4*>(score + (size_t)tile_quad0 * 4);
    const float4 sA = gsc[t];

    __syncthreads();   // drains vmcnt (global_load_lds) for all waves

    // quad t: float4s [5t, 5t+5) — start bank (20t+4j)%32; each 8-lane group
    // covers all 32 banks once per phase -> conflict-free b128 reads.
    const int a0 = t * 5;
    float acc = kl_quad(slog4[a0], slog4[a0 + 1], slog4[a0 + 2],
                        slog4[a0 + 3], slog4[a0 + 4], sA);

    // --- wave (64-lane) shuffle reduction ---
    #pragma unroll
    for (int off = 32; off > 0; off >>= 1) acc += __shfl_down(acc, off, 64);

    __shared__ float wsum[8];
    if (lane == 0) wsum[wave] = acc;
    __syncthreads();
    if (t == 0) {
        float b = 0.0f;
        #pragma unroll
        for (int w = 0; w < 8; ++w) b += wsum[w];
        partial[blockIdx.x] = b;
    }
}

__global__ __launch_bounds__(256) void kl_final_kernel(
    const float* __restrict__ partial,
    float* __restrict__ out) {
    const int t = threadIdx.x;
    // 2048 partials = 512 float4s; thread t sums float4 t and t+256
    const float4* p4 = reinterpret_cast<const float4*>(partial);
    const float4 a = p4[t], b = p4[t + 256];
    float acc = a.x + a.y + a.z + a.w + b.x + b.y + b.z + b.w;

    #pragma unroll
    for (int off = 32; off > 0; off >>= 1) acc += __shfl_down(acc, off, 64);

    __shared__ float wsum[4];
    if ((t & 63) == 0) wsum[t >> 6] = acc;
    __syncthreads();
    if (t == 0) {
        out[0] = (wsum[0] + wsum[1] + wsum[2] + wsum[3]) * (9.0f / (float)kBatch);
    }
}

extern "C" void kernel_launch(void* const* d_in, const int* in_sizes, int n_in,
                              void* d_out, int out_size, void* d_ws, size_t ws_size,
                              hipStream_t stream) {
    const float* score  = (const float*)d_in[0];   // quality_score [B]
    const float* logits = (const float*)d_in[1];   // class_logits [B,5]
    float* out     = (float*)d_out;
    float* partial = (float*)d_ws;                 // kBlocks floats, rewritten every call

    kl_partial_kernel<<<kBlocks, kThreads, 0, stream>>>(score, logits, partial);
    kl_final_kernel<<<1, 256, 0, stream>>>(partial, out);
}